// Round 1
// baseline (341.993 us; speedup 1.0000x reference)
//
#include <hip/hip_runtime.h>
#include <hip/hip_bf16.h>
#include <math.h>

// YOLO decode + hard NMS, exact equivalent of the JAX reference.
// Phase 1: decode boxes + per-box class argmax/max, global scalar reductions.
// Phase 2: scores + 4096-bin histogram. Phase 3 (1 block): threshold-batched
// sorted-sweep greedy NMS (equivalent to repeated argmax with index tie-break).

#define NCLS  80
#define MAXB  100
#define N0    6912     // 48*48*3
#define N1    27648    // 96*96*3
#define N2    110592   // 192*192*3
#define NTOT  145152
#define NB    4096     // histogram bins (linear in score)
#define CAP   4096     // max candidates per sorted batch (LDS capacity)

// ws layout (bytes); total ~3.34 MB
#define WS_BBOX   0                        // NTOT * float4
#define WS_SCORES (NTOT * 16)              // NTOT floats (conf, then scores in-place)
#define WS_CLS    (WS_SCORES + NTOT * 4)   // NTOT ints
#define WS_SCAL   (WS_CLS + NTOT * 4)      // 4 uints (order-encoded floats)
#define WS_HIST   (WS_SCAL + 16)           // NB ints

// Monotone float<->uint encoding so atomicMax/Min on unsigned give float max/min.
__device__ __forceinline__ unsigned fenc(float f) {
    unsigned u = __float_as_uint(f);
    return (u & 0x80000000u) ? ~u : (u | 0x80000000u);
}
__device__ __forceinline__ float fdec(unsigned e) {
    unsigned u = (e & 0x80000000u) ? (e & 0x7FFFFFFFu) : ~e;
    return __uint_as_float(u);
}
// Bin index; identical expression in k2 and k3 -> identical rounding.
__device__ __forceinline__ int binOf(float s, float Smax) {
    int b = (int)((s / Smax) * (float)NB);
    return b > (NB - 1) ? (NB - 1) : b;
}

__global__ __launch_bounds__(256) void k_init(unsigned* __restrict__ scal,
                                              int* __restrict__ hist) {
    int t = blockIdx.x * blockDim.x + threadIdx.x;
    if (t == 0) {
        scal[0] = 0u;           // max maxprob (encoded): 0 < any fenc(finite)
        scal[1] = 0xFFFFFFFFu;  // min maxprob
        scal[2] = 0u;           // max conf
        scal[3] = 0xFFFFFFFFu;  // min conf
    }
    for (int i = t; i < NB; i += blockDim.x * gridDim.x) hist[i] = 0;
}

__global__ __launch_bounds__(256) void k_decode(
        const float* __restrict__ g0, const float* __restrict__ g1,
        const float* __restrict__ g2, const float* __restrict__ anch,
        float* __restrict__ bbox, float* __restrict__ conf,
        int* __restrict__ cls, unsigned* __restrict__ scal) {
    int i = blockIdx.x * 256 + threadIdx.x;   // grid sized exactly: i < NTOT
    const float* p; int H, ar, base;
    if (i < N0)            { base = 0;       p = g0; H = 48;  ar = 2; }
    else if (i < N0 + N1)  { base = N0;      p = g1; H = 96;  ar = 1; }
    else                   { base = N0 + N1; p = g2; H = 192; ar = 0; }
    int j = i - base;
    p += (long)j * 85;
    int cell = j / 3;
    int a = j - cell * 3;
    int ww = cell % H;     // W == H for all three grids
    int hh = cell / H;
    float aw = anch[ar * 6 + a * 2 + 0];
    float ah = anch[ar * 6 + a * 2 + 1];

    float tx = p[0], ty = p[1], tw = p[2], th = p[3], obj = p[4];
    float best = p[5]; int c = 0;
    #pragma unroll 4
    for (int k = 1; k < NCLS; k++) {
        float v = p[5 + k];
        if (v > best) { best = v; c = k; }   // strict > keeps first max (np.argmax)
    }
    // reference: xy = (xy + [w,h]) / [H,W]; wh = exp(wh)*anchor; corners = xy -/+ wh/2
    float xc = (tx + (float)ww) / (float)H;
    float yc = (ty + (float)hh) / (float)H;
    float bw = expf(tw) * aw;
    float bh = expf(th) * ah;
    ((float4*)bbox)[i] = make_float4(xc - bw * 0.5f, yc - bh * 0.5f,
                                     xc + bw * 0.5f, yc + bh * 0.5f);
    conf[i] = obj;
    cls[i]  = c;

    // block reduce {max/min maxprob, max/min conf} -> 4 global atomics
    float mpmax = best, mpmin = best, cmx = obj, cmn = obj;
    for (int off = 32; off > 0; off >>= 1) {
        mpmax = fmaxf(mpmax, __shfl_down(mpmax, off, 64));
        mpmin = fminf(mpmin, __shfl_down(mpmin, off, 64));
        cmx   = fmaxf(cmx,   __shfl_down(cmx,   off, 64));
        cmn   = fminf(cmn,   __shfl_down(cmn,   off, 64));
    }
    __shared__ float sA[4], sB[4], sC[4], sD[4];
    int lane = threadIdx.x & 63, wid = threadIdx.x >> 6;
    if (lane == 0) { sA[wid] = mpmax; sB[wid] = mpmin; sC[wid] = cmx; sD[wid] = cmn; }
    __syncthreads();
    if (threadIdx.x == 0) {
        for (int w = 1; w < 4; w++) {
            sA[0] = fmaxf(sA[0], sA[w]); sB[0] = fminf(sB[0], sB[w]);
            sC[0] = fmaxf(sC[0], sC[w]); sD[0] = fminf(sD[0], sD[w]);
        }
        atomicMax(&scal[0], fenc(sA[0]));
        atomicMin(&scal[1], fenc(sB[0]));
        atomicMax(&scal[2], fenc(sC[0]));
        atomicMin(&scal[3], fenc(sD[0]));
    }
}

__global__ __launch_bounds__(256) void k_score(float* __restrict__ confScores,
                                               const unsigned* __restrict__ scal,
                                               int* __restrict__ hist) {
    int i = blockIdx.x * 256 + threadIdx.x;
    if (i >= NTOT) return;
    float Mx  = fdec(scal[0]), Mn  = fdec(scal[1]);
    float cmx = fdec(scal[2]), cmn = fdec(scal[3]);
    float c = confScores[i];
    float s = fmaxf(c * Mx, c * Mn);          // == max_j conf_i * maxprob_j
    confScores[i] = s;
    // exact global score max: linear in conf -> attained at a conf endpoint
    float Smax = fmaxf(fmaxf(cmx * Mx, cmx * Mn), fmaxf(cmn * Mx, cmn * Mn));
    if (s > 0.0f && Smax > 0.0f) atomicAdd(&hist[binOf(s, Smax)], 1);
}

__global__ __launch_bounds__(1024) void k_nms(
        const float* __restrict__ bbox, const float* __restrict__ scores,
        const int* __restrict__ cls, const unsigned* __restrict__ scal,
        const int* __restrict__ hist, float* __restrict__ out) {
    __shared__ unsigned long long keys[CAP];      // 32 KB
    __shared__ int suf[NB + 1];                   // 16 KB, suffix counts of hist
    __shared__ int grp[1024];
    __shared__ float selX1[MAXB], selY1[MAXB], selX2[MAXB], selY2[MAXB],
                     selA[MAXB], selS[MAXB];
    __shared__ int selC[MAXB];
    __shared__ unsigned long long waveB[16];
    __shared__ int sh_cnt, sh_lo, sh_winner;

    const int tid = threadIdx.x;
    const float Mx  = fdec(scal[0]), Mn  = fdec(scal[1]);
    const float cmx = fdec(scal[2]), cmn = fdec(scal[3]);
    const float Smax = fmaxf(fmaxf(cmx * Mx, cmx * Mn), fmaxf(cmn * Mx, cmn * Mn));

    // ---- suffix sums of hist: suf[b] = sum_{b'>=b} hist[b'], suf[NB]=0 ----
    int b0 = tid * 4;
    int h0 = hist[b0], h1 = hist[b0 + 1], h2 = hist[b0 + 2], h3 = hist[b0 + 3];
    grp[tid] = h0 + h1 + h2 + h3;
    __syncthreads();
    for (int d = 1; d < 1024; d <<= 1) {          // Hillis-Steele suffix scan
        int add = (tid + d < 1024) ? grp[tid + d] : 0;
        __syncthreads();
        grp[tid] += add;
        __syncthreads();
    }
    int gnext = (tid + 1 < 1024) ? grp[tid + 1] : 0;
    suf[b0 + 3] = gnext + h3;
    suf[b0 + 2] = gnext + h3 + h2;
    suf[b0 + 1] = gnext + h3 + h2 + h1;
    suf[b0 + 0] = gnext + h3 + h2 + h1 + h0;
    if (tid == 0) suf[NB] = 0;
    __syncthreads();

    int curSel = 0;
    int hi = NB;
    // ---- batch loop over descending score-bin ranges (exact across batches:
    //      bin ranges are disjoint; within a batch we sort exactly) ----
    while (hi > 0 && curSel < MAXB) {
        if (tid == 0) {
            int sufHi = suf[hi];
            int L = 0, R = hi - 1, res = hi - 1;  // min lo with count<=CAP (suf monotone)
            while (L <= R) {
                int m = (L + R) >> 1;
                if (suf[m] - sufHi <= CAP) { res = m; R = m - 1; } else L = m + 1;
            }
            sh_lo = res;
            sh_cnt = 0;
        }
        __syncthreads();
        const int lo = sh_lo;

        // gather candidates with bin in [lo, hi)
        for (int i = tid; i < NTOT; i += 1024) {
            float s = scores[i];
            if (s > 0.0f) {
                int b = binOf(s, Smax);
                if (b >= lo && b < hi) {
                    int pos = atomicAdd(&sh_cnt, 1);
                    if (pos < CAP)
                        // key: score bits (positive float -> monotone) | ~idx
                        // descending sort => score desc, ties: smallest idx first
                        keys[pos] = ((unsigned long long)__float_as_uint(s) << 32)
                                  | (unsigned long long)(~(unsigned)i);
                }
            }
        }
        __syncthreads();
        int cnt = sh_cnt; if (cnt > CAP) cnt = CAP;
        int n = 1; while (n < cnt) n <<= 1; if (n < 2) n = 2;
        for (int i = cnt + tid; i < n; i += 1024) keys[i] = 0ULL;
        __syncthreads();

        // bitonic sort, descending
        for (int k = 2; k <= n; k <<= 1) {
            for (int j = k >> 1; j > 0; j >>= 1) {
                for (int i = tid; i < n; i += 1024) {
                    int ixj = i ^ j;
                    if (ixj > i) {
                        unsigned long long ka = keys[i], kb = keys[ixj];
                        bool dir = ((i & k) == 0);
                        if ((ka < kb) == dir) { keys[i] = kb; keys[ixj] = ka; }
                    }
                }
                __syncthreads();
            }
        }

        // sorted sweep in chunks of 1024
        for (int base = 0; base < cnt && curSel < MAXB; base += 1024) {
            int t = base + tid;
            bool alive = (t < cnt);
            float x1 = 0.f, y1 = 0.f, x2 = 0.f, y2 = 0.f, area = 0.f, sc = 0.f;
            int mycls = 0;
            if (alive) {
                unsigned long long key = keys[t];
                int myidx = (int)(~(unsigned)(key & 0xFFFFFFFFull));
                sc = __uint_as_float((unsigned)(key >> 32));
                float4 bx = ((const float4*)bbox)[myidx];
                x1 = bx.x; y1 = bx.y; x2 = bx.z; y2 = bx.w;
                area = (x2 - x1) * (y2 - y1);
                mycls = cls[myidx];
                // pre-test vs already-selected boxes
                for (int s2 = 0; s2 < curSel; s2++) {
                    float iw = fminf(x2, selX2[s2]) - fmaxf(x1, selX1[s2]);
                    float ih = fminf(y2, selY2[s2]) - fmaxf(y1, selY1[s2]);
                    iw = fmaxf(iw, 0.f); ih = fmaxf(ih, 0.f);
                    float inter = iw * ih;
                    float iou = inter / (area + selA[s2] - inter);
                    if (iou > 0.5f) { alive = false; break; }
                }
            }
            // serial acceptance: first alive candidate is next selection
            while (true) {
                unsigned long long bal = __ballot(alive);
                int lane = tid & 63, wid = tid >> 6;
                if (lane == 0) waveB[wid] = bal;
                __syncthreads();
                if (tid == 0) {
                    int w = -1;
                    for (int wv = 0; wv < 16; wv++)
                        if (waveB[wv]) { w = wv * 64 + (__ffsll(waveB[wv]) - 1); break; }
                    sh_winner = w;
                }
                __syncthreads();
                int winner = sh_winner;
                if (winner < 0) break;
                if (tid == winner) {
                    selX1[curSel] = x1; selY1[curSel] = y1;
                    selX2[curSel] = x2; selY2[curSel] = y2;
                    selA[curSel] = area; selS[curSel] = sc; selC[curSel] = mycls;
                }
                __syncthreads();
                if (alive) {  // winner suppresses itself via IoU==1
                    float iw = fminf(x2, selX2[curSel]) - fmaxf(x1, selX1[curSel]);
                    float ih = fminf(y2, selY2[curSel]) - fmaxf(y1, selY1[curSel]);
                    iw = fmaxf(iw, 0.f); ih = fmaxf(ih, 0.f);
                    float inter = iw * ih;
                    float iou = inter / (area + selA[curSel] - inter);
                    if (iou > 0.5f) alive = false;
                }
                curSel++;
                if (curSel >= MAXB) break;
            }
            __syncthreads();
        }
        hi = lo;
    }
    __syncthreads();

    // outputs (all float32): boxes[100*4] | scores[100] | classes[100] | num_valid
    for (int k = tid; k < MAXB; k += 1024) {
        bool v = k < curSel;
        out[4 * k + 0] = v ? selX1[k] : 0.f;
        out[4 * k + 1] = v ? selY1[k] : 0.f;
        out[4 * k + 2] = v ? selX2[k] : 0.f;
        out[4 * k + 3] = v ? selY2[k] : 0.f;
        out[400 + k] = v ? selS[k] : 0.f;
        out[500 + k] = v ? (float)selC[k] : 0.f;
    }
    if (tid == 0) out[600] = (float)curSel;
}

extern "C" void kernel_launch(void* const* d_in, const int* in_sizes, int n_in,
                              void* d_out, int out_size, void* d_ws, size_t ws_size,
                              hipStream_t stream) {
    const float* g0   = (const float*)d_in[0];
    const float* g1   = (const float*)d_in[1];
    const float* g2   = (const float*)d_in[2];
    const float* anch = (const float*)d_in[3];
    char* ws = (char*)d_ws;
    float*    bbox   = (float*)(ws + WS_BBOX);
    float*    scores = (float*)(ws + WS_SCORES);
    int*      cls    = (int*)(ws + WS_CLS);
    unsigned* scal   = (unsigned*)(ws + WS_SCAL);
    int*      hist   = (int*)(ws + WS_HIST);
    float*    out    = (float*)d_out;

    k_init  <<<16, 256, 0, stream>>>(scal, hist);
    k_decode<<<NTOT / 256, 256, 0, stream>>>(g0, g1, g2, anch, bbox, scores, cls, scal);
    k_score <<<NTOT / 256, 256, 0, stream>>>(scores, scal, hist);
    k_nms   <<<1, 1024, 0, stream>>>(bbox, scores, cls, scal, hist, out);
}

// Round 2
// 327.267 us; speedup vs baseline: 1.0450x; 1.0450x over previous
//
#include <hip/hip_runtime.h>
#include <hip/hip_bf16.h>
#include <math.h>

// YOLO decode + hard NMS, exact equivalent of the JAX reference.
// Pipeline: init -> decode (LDS-staged coalesced) -> score+hist ->
// thresh (1 blk) -> compact (top<=CAP cands to global) -> nms (1 blk:
// bitonic sort + wave-serial sweep; exact batch fallback over lower bins).

#define NCLS  80
#define MAXB  100
#define N0    6912     // 48*48*3
#define N1    27648    // 96*96*3
#define N2    110592   // 192*192*3
#define NTOT  145152
#define NB    4096     // histogram bins (linear in score)
#define CAP   2048     // max candidates per sorted batch

// ws layout (bytes), end ~3.37 MB
#define WS_BBOX   0
#define WS_SCORES (NTOT * 16)
#define WS_CLS    (WS_SCORES + NTOT * 4)
#define WS_SCAL   (WS_CLS + NTOT * 4)
#define WS_GCNT   (WS_SCAL + 16)
#define WS_HIST   (WS_GCNT + 16)
#define WS_SUF    (WS_HIST + NB * 4)
#define WS_META   (WS_SUF + (NB + 4) * 4)
#define WS_CAND   (WS_META + 16)

// Monotone float<->uint encoding so atomicMax/Min on unsigned give float max/min.
__device__ __forceinline__ unsigned fenc(float f) {
    unsigned u = __float_as_uint(f);
    return (u & 0x80000000u) ? ~u : (u | 0x80000000u);
}
__device__ __forceinline__ float fdec(unsigned e) {
    unsigned u = (e & 0x80000000u) ? (e & 0x7FFFFFFFu) : ~e;
    return __uint_as_float(u);
}
// Bin index; identical expression everywhere -> identical rounding.
__device__ __forceinline__ int binOf(float s, float Smax) {
    int b = (int)((s / Smax) * (float)NB);
    return b > (NB - 1) ? (NB - 1) : b;
}
__device__ __forceinline__ float smaxOf(const unsigned* scal, float Mx, float Mn) {
    float cmx = fdec(scal[2]), cmn = fdec(scal[3]);
    return fmaxf(fmaxf(cmx * Mx, cmx * Mn), fmaxf(cmn * Mx, cmn * Mn));
}

__global__ __launch_bounds__(256) void k_init(unsigned* __restrict__ scal,
                                              int* __restrict__ gcnt,
                                              int* __restrict__ hist) {
    int t = blockIdx.x * 256 + threadIdx.x;
    if (t == 0) {
        scal[0] = 0u;           // max maxprob (encoded)
        scal[1] = 0xFFFFFFFFu;  // min maxprob
        scal[2] = 0u;           // max conf
        scal[3] = 0xFFFFFFFFu;  // min conf
        gcnt[0] = 0;
    }
    if (t < NB) hist[t] = 0;
}

// One 64-thread block decodes 64 consecutive boxes of one grid.
// Tile counts: 108 / 432 / 1728 (grid sizes all divisible by 64).
__global__ __launch_bounds__(64) void k_decode(
        const float* __restrict__ g0, const float* __restrict__ g1,
        const float* __restrict__ g2, const float* __restrict__ anch,
        float* __restrict__ bbox, float* __restrict__ conf,
        int* __restrict__ cls, unsigned* __restrict__ scal) {
    __shared__ float4 sm4[1360];            // 64 boxes * 85 words = 21760 B
    const int lane = threadIdx.x;
    const int tile = blockIdx.x;
    const float* p; int H, ar, t0, base;
    if (tile < 108)      { p = g0; H = 48;  ar = 2; t0 = 0;   base = 0; }
    else if (tile < 540) { p = g1; H = 96;  ar = 1; t0 = 108; base = N0; }
    else                 { p = g2; H = 192; ar = 0; t0 = 540; base = N0 + N1; }
    const int lt = tile - t0;
    const float4* src = (const float4*)(p + (size_t)lt * 5440);  // 16B-aligned
    for (int w = lane; w < 1360; w += 64) sm4[w] = src[w];       // coalesced
    __syncthreads();

    const float* row = (const float*)sm4 + lane * 85;  // stride 85: 2-way bank alias = free
    float tx = row[0], ty = row[1], tw = row[2], th = row[3], obj = row[4];
    float best = row[5]; int c = 0;
    #pragma unroll 4
    for (int k = 1; k < NCLS; k++) {
        float v = row[5 + k];
        if (v > best) { best = v; c = k; }   // strict > = first max (np.argmax)
    }
    int j = lt * 64 + lane;                  // box index within its grid
    int i = base + j;
    int cell = j / 3;
    int a = j - cell * 3;
    int hh = cell / H;
    int ww = cell - hh * H;                  // W == H
    float aw = anch[ar * 6 + a * 2 + 0];
    float ah = anch[ar * 6 + a * 2 + 1];
    float xc = (tx + (float)ww) / (float)H;
    float yc = (ty + (float)hh) / (float)H;
    float bw = expf(tw) * aw;
    float bh = expf(th) * ah;
    ((float4*)bbox)[i] = make_float4(xc - bw * 0.5f, yc - bh * 0.5f,
                                     xc + bw * 0.5f, yc + bh * 0.5f);
    conf[i] = obj;
    cls[i]  = c;

    // single-wave reduce {max/min maxprob, max/min conf} -> 4 atomics
    float mpmax = best, mpmin = best, cmx = obj, cmn = obj;
    for (int off = 32; off; off >>= 1) {
        mpmax = fmaxf(mpmax, __shfl_down(mpmax, off));
        mpmin = fminf(mpmin, __shfl_down(mpmin, off));
        cmx   = fmaxf(cmx,   __shfl_down(cmx,   off));
        cmn   = fminf(cmn,   __shfl_down(cmn,   off));
    }
    if (lane == 0) {
        atomicMax(&scal[0], fenc(mpmax));
        atomicMin(&scal[1], fenc(mpmin));
        atomicMax(&scal[2], fenc(cmx));
        atomicMin(&scal[3], fenc(cmn));
    }
}

__global__ __launch_bounds__(256) void k_score(float* __restrict__ scores,
                                               const unsigned* __restrict__ scal,
                                               int* __restrict__ hist) {
    int i = blockIdx.x * 256 + threadIdx.x;
    if (i >= NTOT) return;
    float Mx = fdec(scal[0]), Mn = fdec(scal[1]);
    float c = scores[i];
    float s = fmaxf(c * Mx, c * Mn);          // == max_j conf_i * maxprob_j
    scores[i] = s;
    float Smax = smaxOf(scal, Mx, Mn);        // exact global score max (linear in conf)
    if (s > 0.0f && Smax > 0.0f) atomicAdd(&hist[binOf(s, Smax)], 1);
}

__global__ __launch_bounds__(1024) void k_thresh(const int* __restrict__ hist,
                                                 int* __restrict__ suf,
                                                 int* __restrict__ meta) {
    __shared__ int grp[1024];
    const int tid = threadIdx.x;
    int b0 = tid * 4;
    int h0 = hist[b0], h1 = hist[b0 + 1], h2 = hist[b0 + 2], h3 = hist[b0 + 3];
    grp[tid] = h0 + h1 + h2 + h3;
    __syncthreads();
    for (int d = 1; d < 1024; d <<= 1) {      // Hillis-Steele suffix scan
        int add = (tid + d < 1024) ? grp[tid + d] : 0;
        __syncthreads();
        grp[tid] += add;
        __syncthreads();
    }
    int gnext = (tid + 1 < 1024) ? grp[tid + 1] : 0;
    suf[b0 + 3] = gnext + h3;
    suf[b0 + 2] = gnext + h3 + h2;
    suf[b0 + 1] = gnext + h3 + h2 + h1;
    suf[b0 + 0] = gnext + h3 + h2 + h1 + h0;
    if (tid == 0) suf[NB] = 0;
    __syncthreads();                          // block-scope fence: suf visible
    if (tid == 0) {                           // min lo with suffix count <= CAP
        int L = 0, R = NB - 1, res = NB - 1;
        while (L <= R) {
            int m = (L + R) >> 1;
            if (suf[m] <= CAP) { res = m; R = m - 1; } else L = m + 1;
        }
        meta[0] = res;
    }
}

__global__ __launch_bounds__(256) void k_compact(
        const float* __restrict__ scores, const unsigned* __restrict__ scal,
        const int* __restrict__ meta, int* __restrict__ gcnt,
        unsigned long long* __restrict__ cand) {
    int i = blockIdx.x * 256 + threadIdx.x;
    if (i >= NTOT) return;
    float Mx = fdec(scal[0]), Mn = fdec(scal[1]);
    float Smax = smaxOf(scal, Mx, Mn);
    float s = scores[i];
    int lo = meta[0];
    if (s > 0.0f && Smax > 0.0f) {
        int b = binOf(s, Smax);
        if (b >= lo) {
            int pos = atomicAdd(gcnt, 1);     // compiler wave-aggregates (m20)
            if (pos < CAP)
                // descending sort key: score bits | ~idx (ties: smallest idx first)
                cand[pos] = ((unsigned long long)__float_as_uint(s) << 32)
                          | (unsigned long long)(~(unsigned)i);
        }
    }
}

__global__ __launch_bounds__(256) void k_nms(
        const float* __restrict__ bbox, const float* __restrict__ scores,
        const int* __restrict__ cls, const unsigned* __restrict__ scal,
        const int* __restrict__ suf, const int* __restrict__ meta,
        const int* __restrict__ gcnt, const unsigned long long* __restrict__ cand,
        float* __restrict__ out) {
    __shared__ unsigned long long keys[CAP];  // 16 KB
    __shared__ float selX1[MAXB], selY1[MAXB], selX2[MAXB], selY2[MAXB],
                     selA[MAXB], selS[MAXB];
    __shared__ int selC[MAXB];
    __shared__ int sh_nsel, sh_cnt, sh_lo;

    const int tid = threadIdx.x;
    const float Mx = fdec(scal[0]), Mn = fdec(scal[1]);
    const float Smax = smaxOf(scal, Mx, Mn);
    int nsel = 0;
    int lo = meta[0], hi = NB;
    bool first = true;
    if (tid == 0) sh_nsel = 0;

    while (true) {
        int cnt;
        if (first) {
            cnt = *gcnt; if (cnt > CAP) cnt = CAP;
            for (int i = tid; i < cnt; i += 256) keys[i] = cand[i];
        } else {
            // exact fallback: gather bins [lo,hi) from global scores (cold path)
            if (tid == 0) sh_cnt = 0;
            __syncthreads();
            for (int i = tid; i < NTOT; i += 256) {
                float s = scores[i];
                if (s > 0.0f) {
                    int b = binOf(s, Smax);
                    if (b >= lo && b < hi) {
                        int pos = atomicAdd(&sh_cnt, 1);
                        if (pos < CAP)
                            keys[pos] = ((unsigned long long)__float_as_uint(s) << 32)
                                      | (unsigned long long)(~(unsigned)i);
                    }
                }
            }
            __syncthreads();
            cnt = sh_cnt; if (cnt > CAP) cnt = CAP;
        }
        int n = 2; while (n < cnt) n <<= 1;
        for (int i = cnt + tid; i < n; i += 256) keys[i] = 0ULL;
        __syncthreads();

        // bitonic sort, descending
        for (int k = 2; k <= n; k <<= 1) {
            for (int j = k >> 1; j > 0; j >>= 1) {
                for (int i = tid; i < n; i += 256) {
                    int ixj = i ^ j;
                    if (ixj > i) {
                        unsigned long long ka = keys[i], kb = keys[ixj];
                        bool dir = ((i & k) == 0);
                        if ((ka < kb) == dir) { keys[i] = kb; keys[ixj] = ka; }
                    }
                }
                __syncthreads();
            }
        }

        // wave-serial sweep: wave 0 only, in-register ballot/shfl, no barriers
        if (tid < 64) {
            int ns = nsel;
            for (int bpos = 0; bpos < cnt && ns < MAXB; bpos += 64) {
                int t = bpos + tid;
                bool alive = (t < cnt);
                float x1 = 0.f, y1 = 0.f, x2 = 0.f, y2 = 0.f, area = 0.f, sc = 0.f;
                int cl = 0;
                if (alive) {
                    unsigned long long key = keys[t];
                    unsigned idx = ~(unsigned)key;
                    sc = __uint_as_float((unsigned)(key >> 32));
                    float4 bx = ((const float4*)bbox)[idx];
                    x1 = bx.x; y1 = bx.y; x2 = bx.z; y2 = bx.w;
                    area = (x2 - x1) * (y2 - y1);
                    cl = cls[idx];
                    for (int s2 = 0; s2 < ns; s2++) {   // pre-test vs prior selections
                        float iw = fminf(x2, selX2[s2]) - fmaxf(x1, selX1[s2]);
                        float ih = fminf(y2, selY2[s2]) - fmaxf(y1, selY1[s2]);
                        iw = fmaxf(iw, 0.f); ih = fmaxf(ih, 0.f);
                        float inter = iw * ih;
                        if (inter / (area + selA[s2] - inter) > 0.5f) { alive = false; break; }
                    }
                }
                while (ns < MAXB) {
                    unsigned long long bal = __ballot(alive);
                    if (!bal) break;
                    int w = __ffsll(bal) - 1;           // first alive = next selection
                    float wx1 = __shfl(x1, w), wy1 = __shfl(y1, w);
                    float wx2 = __shfl(x2, w), wy2 = __shfl(y2, w);
                    float wa  = __shfl(area, w), wsc = __shfl(sc, w);
                    int   wc  = __shfl(cl, w);
                    if (tid == 0) {
                        selX1[ns] = wx1; selY1[ns] = wy1; selX2[ns] = wx2; selY2[ns] = wy2;
                        selA[ns] = wa; selS[ns] = wsc; selC[ns] = wc;
                    }
                    if (alive) {                        // winner kills itself (IoU=1)
                        float iw = fminf(x2, wx2) - fmaxf(x1, wx1);
                        float ih = fminf(y2, wy2) - fmaxf(y1, wy1);
                        iw = fmaxf(iw, 0.f); ih = fmaxf(ih, 0.f);
                        float inter = iw * ih;
                        if (inter / (area + wa - inter) > 0.5f) alive = false;
                    }
                    ns++;
                }
            }
            if (tid == 0) sh_nsel = ns;
        }
        __syncthreads();
        nsel = sh_nsel;
        hi = lo;
        if (nsel >= MAXB || hi == 0) break;
        if (tid == 0) {                       // next batch's lo via suffix counts
            int sufHi = suf[hi];
            int L = 0, R = hi - 1, res = hi - 1;
            while (L <= R) {
                int m = (L + R) >> 1;
                if (suf[m] - sufHi <= CAP) { res = m; R = m - 1; } else L = m + 1;
            }
            sh_lo = res;
        }
        __syncthreads();
        lo = sh_lo;
        first = false;
        __syncthreads();
    }
    __syncthreads();

    // outputs: boxes[100*4] | scores[100] | classes[100] | num_valid (all fp32)
    for (int k = tid; k < MAXB; k += 256) {
        bool v = k < nsel;
        out[4 * k + 0] = v ? selX1[k] : 0.f;
        out[4 * k + 1] = v ? selY1[k] : 0.f;
        out[4 * k + 2] = v ? selX2[k] : 0.f;
        out[4 * k + 3] = v ? selY2[k] : 0.f;
        out[400 + k] = v ? selS[k] : 0.f;
        out[500 + k] = v ? (float)selC[k] : 0.f;
    }
    if (tid == 0) out[600] = (float)nsel;
}

extern "C" void kernel_launch(void* const* d_in, const int* in_sizes, int n_in,
                              void* d_out, int out_size, void* d_ws, size_t ws_size,
                              hipStream_t stream) {
    const float* g0   = (const float*)d_in[0];
    const float* g1   = (const float*)d_in[1];
    const float* g2   = (const float*)d_in[2];
    const float* anch = (const float*)d_in[3];
    char* ws = (char*)d_ws;
    float*    bbox   = (float*)(ws + WS_BBOX);
    float*    scores = (float*)(ws + WS_SCORES);
    int*      cls    = (int*)(ws + WS_CLS);
    unsigned* scal   = (unsigned*)(ws + WS_SCAL);
    int*      gcnt   = (int*)(ws + WS_GCNT);
    int*      hist   = (int*)(ws + WS_HIST);
    int*      suf    = (int*)(ws + WS_SUF);
    int*      meta   = (int*)(ws + WS_META);
    unsigned long long* cand = (unsigned long long*)(ws + WS_CAND);
    float*    out    = (float*)d_out;

    k_init   <<<16, 256, 0, stream>>>(scal, gcnt, hist);
    k_decode <<<NTOT / 64, 64, 0, stream>>>(g0, g1, g2, anch, bbox, scores, cls, scal);
    k_score  <<<NTOT / 256, 256, 0, stream>>>(scores, scal, hist);
    k_thresh <<<1, 1024, 0, stream>>>(hist, suf, meta);
    k_compact<<<NTOT / 256, 256, 0, stream>>>(scores, scal, meta, gcnt, cand);
    k_nms    <<<1, 256, 0, stream>>>(bbox, scores, cls, scal, suf, meta, gcnt, cand, out);
}

// Round 3
// 211.901 us; speedup vs baseline: 1.6139x; 1.5444x over previous
//
#include <hip/hip_runtime.h>
#include <hip/hip_bf16.h>
#include <math.h>

// YOLO decode + hard NMS, exact equivalent of the JAX reference.
// R3: all same-line contended atomics removed. decode -> per-block partials
// (plain stores) -> k_reduce (1 blk). hist sharded 8x. compact positions
// derived from exact suffix counts + per-bin counters (spread lines).

#define NCLS  80
#define MAXB  100
#define N0    6912     // 48*48*3
#define N1    27648    // 96*96*3
#define NTOT  145152
#define NTILE 2268     // 64-box tiles
#define NB    4096     // histogram bins (linear in score)
#define CAP   2048     // max candidates per sorted batch
#define NEGF  -3.402823466e38f
#define POSF   3.402823466e38f

// ws layout (bytes), total ~3.70 MB
#define WS_BBOX 0
#define WS_CONF (NTOT * 16)
#define WS_CLS  (WS_CONF + NTOT * 4)
#define WS_SCAL (WS_CLS + NTOT * 4)
#define WS_PART (WS_SCAL + 16)
#define WS_HIST (WS_PART + NTILE * 16)       // 8 shards * NB ints
#define WS_BINC (WS_HIST + 8 * NB * 4)       // NB ints (contiguous after HIST)
#define WS_SUF  (WS_BINC + NB * 4)
#define WS_META (WS_SUF + (NB + 2) * 4)
#define WS_CAND (WS_META + 16)

// Bin index; identical expression everywhere -> identical rounding.
__device__ __forceinline__ int binOf(float s, float Smax) {
    int b = (int)((s / Smax) * (float)NB);
    return b > (NB - 1) ? (NB - 1) : b;
}
__device__ __forceinline__ float smaxOf(const float* scal) {
    float Mx = scal[0], Mn = scal[1], cmx = scal[2], cmn = scal[3];
    return fmaxf(fmaxf(cmx * Mx, cmx * Mn), fmaxf(cmn * Mx, cmn * Mn));
}

__global__ __launch_bounds__(256) void k_init(int* __restrict__ histAll) {
    int t = blockIdx.x * 256 + threadIdx.x;   // grid 144*256 == 9*NB exactly
    histAll[t] = 0;                           // zeros hist shards + binCtr
}

// One 256-thread block decodes one 64-box tile: 4 lanes per box.
__global__ __launch_bounds__(256) void k_decode(
        const float* __restrict__ g0, const float* __restrict__ g1,
        const float* __restrict__ g2, const float* __restrict__ anch,
        float* __restrict__ bbox, float* __restrict__ conf,
        int* __restrict__ cls, float* __restrict__ part) {
    __shared__ float sm[5440];                // 64 boxes * 85 ch
    __shared__ float red[16];
    const int tid = threadIdx.x;
    const int tile = blockIdx.x;
    const float* p; int H, ar, ibase, lt;
    if (tile < 108)      { p = g0; H = 48;  ar = 2; ibase = 0;       lt = tile; }
    else if (tile < 540) { p = g1; H = 96;  ar = 1; ibase = N0;      lt = tile - 108; }
    else                 { p = g2; H = 192; ar = 0; ibase = N0 + N1; lt = tile - 540; }
    const float4* src = (const float4*)(p + (size_t)lt * 5440);   // 16B-aligned
    for (int w = tid; w < 1360; w += 256) ((float4*)sm)[w] = src[w];  // coalesced
    __syncthreads();

    const int b = tid >> 2, pp = tid & 3;     // 4 lanes per box (contiguous, same wave)
    const float* row = sm + b * 85;           // odd stride: benign bank aliasing
    const int cb = pp * 20;
    float best = row[5 + cb]; int c = cb;
    #pragma unroll
    for (int k = 1; k < 20; k++) {
        float v = row[5 + cb + k];
        if (v > best) { best = v; c = cb + k; }   // strict > = first max (np.argmax)
    }
    #pragma unroll
    for (int off = 1; off < 4; off <<= 1) {   // combine 4 parts; ties -> lower class
        float ov = __shfl_xor(best, off);
        int   oc = __shfl_xor(c, off);
        if (ov > best || (ov == best && oc < c)) { best = ov; c = oc; }
    }
    float cmx = NEGF, cmn = POSF;
    if (pp == 0) {
        float tx = row[0], ty = row[1], tw = row[2], th = row[3], obj = row[4];
        int j = lt * 64 + b;                  // box index within its grid
        int cell = j / 3, a = j - cell * 3;
        int hh = cell / H, ww = cell - hh * H;   // W == H
        float aw = anch[ar * 6 + a * 2], ah = anch[ar * 6 + a * 2 + 1];
        float xc = (tx + (float)ww) / (float)H;
        float yc = (ty + (float)hh) / (float)H;
        float bw = expf(tw) * aw, bh = expf(th) * ah;
        int i = ibase + j;
        ((float4*)bbox)[i] = make_float4(xc - bw * 0.5f, yc - bh * 0.5f,
                                         xc + bw * 0.5f, yc + bh * 0.5f);
        conf[i] = obj;
        cls[i]  = c;
        cmx = obj; cmn = obj;
    }
    // block reduce {max/min class-best, max/min conf} -> plain stores (NO atomics)
    float mpmax = best, mpmin = best;
    for (int off = 32; off; off >>= 1) {
        mpmax = fmaxf(mpmax, __shfl_down(mpmax, off));
        mpmin = fminf(mpmin, __shfl_down(mpmin, off));
        cmx   = fmaxf(cmx,   __shfl_down(cmx,   off));
        cmn   = fminf(cmn,   __shfl_down(cmn,   off));
    }
    const int lane = tid & 63, wid = tid >> 6;
    if (lane == 0) {
        red[wid * 4 + 0] = mpmax; red[wid * 4 + 1] = mpmin;
        red[wid * 4 + 2] = cmx;   red[wid * 4 + 3] = cmn;
    }
    __syncthreads();
    if (tid == 0) {
        float a0 = red[0], a1 = red[1], a2 = red[2], a3 = red[3];
        for (int w = 1; w < 4; w++) {
            a0 = fmaxf(a0, red[w * 4 + 0]); a1 = fminf(a1, red[w * 4 + 1]);
            a2 = fmaxf(a2, red[w * 4 + 2]); a3 = fminf(a3, red[w * 4 + 3]);
        }
        part[tile * 4 + 0] = a0; part[tile * 4 + 1] = a1;
        part[tile * 4 + 2] = a2; part[tile * 4 + 3] = a3;
    }
}

__global__ __launch_bounds__(256) void k_reduce(const float* __restrict__ part,
                                                float* __restrict__ scal) {
    __shared__ float red[16];
    const int tid = threadIdx.x;
    float a0 = NEGF, a1 = POSF, a2 = NEGF, a3 = POSF;
    for (int b = tid; b < NTILE; b += 256) {
        a0 = fmaxf(a0, part[b * 4 + 0]); a1 = fminf(a1, part[b * 4 + 1]);
        a2 = fmaxf(a2, part[b * 4 + 2]); a3 = fminf(a3, part[b * 4 + 3]);
    }
    for (int off = 32; off; off >>= 1) {
        a0 = fmaxf(a0, __shfl_down(a0, off)); a1 = fminf(a1, __shfl_down(a1, off));
        a2 = fmaxf(a2, __shfl_down(a2, off)); a3 = fminf(a3, __shfl_down(a3, off));
    }
    const int lane = tid & 63, wid = tid >> 6;
    if (lane == 0) {
        red[wid * 4 + 0] = a0; red[wid * 4 + 1] = a1;
        red[wid * 4 + 2] = a2; red[wid * 4 + 3] = a3;
    }
    __syncthreads();
    if (tid == 0) {
        for (int w = 1; w < 4; w++) {
            a0 = fmaxf(a0, red[w * 4 + 0]); a1 = fminf(a1, red[w * 4 + 1]);
            a2 = fmaxf(a2, red[w * 4 + 2]); a3 = fminf(a3, red[w * 4 + 3]);
        }
        scal[0] = a0; scal[1] = a1; scal[2] = a2; scal[3] = a3;
    }
}

__global__ __launch_bounds__(256) void k_hist(const float* __restrict__ conf,
                                              const float* __restrict__ scal,
                                              int* __restrict__ hist) {
    int i = blockIdx.x * 256 + threadIdx.x;   // grid == NTOT/256 exactly
    float Mx = scal[0], Mn = scal[1];
    float Smax = smaxOf(scal);
    float c = conf[i];
    float s = fmaxf(c * Mx, c * Mn);          // == max_j conf_i * maxprob_j
    if (s > 0.0f && Smax > 0.0f)              // 8-way sharded to spread lines
        atomicAdd(&hist[((blockIdx.x & 7) << 12) + binOf(s, Smax)], 1);
}

__global__ __launch_bounds__(1024) void k_thresh(const int* __restrict__ hist,
                                                 int* __restrict__ suf,
                                                 int* __restrict__ meta) {
    __shared__ int grp[1024];
    const int tid = threadIdx.x;
    int b0 = tid * 4;
    int h[4];
    #pragma unroll
    for (int q = 0; q < 4; q++) {             // sum the 8 shards
        int s = 0;
        #pragma unroll
        for (int sh = 0; sh < 8; sh++) s += hist[sh * NB + b0 + q];
        h[q] = s;
    }
    grp[tid] = h[0] + h[1] + h[2] + h[3];
    __syncthreads();
    for (int d = 1; d < 1024; d <<= 1) {      // Hillis-Steele suffix scan
        int add = (tid + d < 1024) ? grp[tid + d] : 0;
        __syncthreads();
        grp[tid] += add;
        __syncthreads();
    }
    int gnext = (tid + 1 < 1024) ? grp[tid + 1] : 0;
    suf[b0 + 3] = gnext + h[3];
    suf[b0 + 2] = gnext + h[3] + h[2];
    suf[b0 + 1] = gnext + h[3] + h[2] + h[1];
    suf[b0 + 0] = gnext + h[3] + h[2] + h[1] + h[0];
    if (tid == 0) suf[NB] = 0;
    __syncthreads();
    if (tid == 0) {                           // min lo with suffix count <= CAP
        int L = 0, R = NB - 1, res = NB - 1;
        while (L <= R) {
            int m = (L + R) >> 1;
            if (suf[m] <= CAP) { res = m; R = m - 1; } else L = m + 1;
        }
        meta[0] = res;
    }
}

__global__ __launch_bounds__(256) void k_compact(
        const float* __restrict__ conf, const float* __restrict__ scal,
        const int* __restrict__ suf, const int* __restrict__ meta,
        int* __restrict__ binCtr, unsigned long long* __restrict__ cand) {
    int i = blockIdx.x * 256 + threadIdx.x;
    float Mx = scal[0], Mn = scal[1];
    float Smax = smaxOf(scal);
    float c = conf[i];
    float s = fmaxf(c * Mx, c * Mn);
    int lo = meta[0];
    if (s > 0.0f && Smax > 0.0f) {
        int b = binOf(s, Smax);
        if (b >= lo) {
            // exact position: (#cands in higher bins) + rank within bin.
            // atomics spread across ~many bin lines -> low contention.
            int pos = suf[b + 1] + atomicAdd(&binCtr[b], 1);
            if (pos < CAP)
                // descending sort key: score bits | ~idx (ties: smallest idx first)
                cand[pos] = ((unsigned long long)__float_as_uint(s) << 32)
                          | (unsigned long long)(~(unsigned)i);
        }
    }
}

__global__ __launch_bounds__(256) void k_nms(
        const float* __restrict__ bbox, const float* __restrict__ conf,
        const int* __restrict__ cls, const float* __restrict__ scal,
        const int* __restrict__ suf, const int* __restrict__ meta,
        const unsigned long long* __restrict__ cand, float* __restrict__ out) {
    __shared__ unsigned long long keys[CAP];  // 16 KB
    __shared__ float selX1[MAXB], selY1[MAXB], selX2[MAXB], selY2[MAXB],
                     selA[MAXB], selS[MAXB];
    __shared__ int selC[MAXB];
    __shared__ int sh_nsel, sh_cnt, sh_lo;

    const int tid = threadIdx.x;
    const float Mx = scal[0], Mn = scal[1];
    const float Smax = smaxOf(scal);
    int nsel = 0;
    int lo = meta[0], hi = NB;
    bool first = true;
    if (tid == 0) sh_nsel = 0;

    while (true) {
        int cnt;
        if (first) {
            cnt = suf[lo]; if (cnt > CAP) cnt = CAP;
            for (int i = tid; i < cnt; i += 256) keys[i] = cand[i];
        } else {
            // exact fallback: gather bins [lo,hi) recomputing s from conf (cold)
            if (tid == 0) sh_cnt = 0;
            __syncthreads();
            for (int i = tid; i < NTOT; i += 256) {
                float c = conf[i];
                float s = fmaxf(c * Mx, c * Mn);
                if (s > 0.0f && Smax > 0.0f) {
                    int b = binOf(s, Smax);
                    if (b >= lo && b < hi) {
                        int pos = atomicAdd(&sh_cnt, 1);
                        if (pos < CAP)
                            keys[pos] = ((unsigned long long)__float_as_uint(s) << 32)
                                      | (unsigned long long)(~(unsigned)i);
                    }
                }
            }
            __syncthreads();
            cnt = sh_cnt; if (cnt > CAP) cnt = CAP;
        }
        int n = 2; while (n < cnt) n <<= 1;
        for (int i = cnt + tid; i < n; i += 256) keys[i] = 0ULL;
        __syncthreads();

        // bitonic sort, descending
        for (int k = 2; k <= n; k <<= 1) {
            for (int j = k >> 1; j > 0; j >>= 1) {
                for (int i = tid; i < n; i += 256) {
                    int ixj = i ^ j;
                    if (ixj > i) {
                        unsigned long long ka = keys[i], kb = keys[ixj];
                        bool dir = ((i & k) == 0);
                        if ((ka < kb) == dir) { keys[i] = kb; keys[ixj] = ka; }
                    }
                }
                __syncthreads();
            }
        }

        // wave-serial sweep: wave 0 only, in-register ballot/shfl, no barriers
        if (tid < 64) {
            int ns = nsel;
            for (int bpos = 0; bpos < cnt && ns < MAXB; bpos += 64) {
                int t = bpos + tid;
                bool alive = (t < cnt);
                float x1 = 0.f, y1 = 0.f, x2 = 0.f, y2 = 0.f, area = 0.f, sc = 0.f;
                int cl = 0;
                if (alive) {
                    unsigned long long key = keys[t];
                    unsigned idx = ~(unsigned)key;
                    sc = __uint_as_float((unsigned)(key >> 32));
                    float4 bx = ((const float4*)bbox)[idx];
                    x1 = bx.x; y1 = bx.y; x2 = bx.z; y2 = bx.w;
                    area = (x2 - x1) * (y2 - y1);
                    cl = cls[idx];
                    for (int s2 = 0; s2 < ns; s2++) {   // pre-test vs prior selections
                        float iw = fminf(x2, selX2[s2]) - fmaxf(x1, selX1[s2]);
                        float ih = fminf(y2, selY2[s2]) - fmaxf(y1, selY1[s2]);
                        iw = fmaxf(iw, 0.f); ih = fmaxf(ih, 0.f);
                        float inter = iw * ih;
                        if (inter / (area + selA[s2] - inter) > 0.5f) { alive = false; break; }
                    }
                }
                while (ns < MAXB) {
                    unsigned long long bal = __ballot(alive);
                    if (!bal) break;
                    int w = __ffsll(bal) - 1;           // first alive = next selection
                    float wx1 = __shfl(x1, w), wy1 = __shfl(y1, w);
                    float wx2 = __shfl(x2, w), wy2 = __shfl(y2, w);
                    float wa  = __shfl(area, w), wsc = __shfl(sc, w);
                    int   wc  = __shfl(cl, w);
                    if (tid == 0) {
                        selX1[ns] = wx1; selY1[ns] = wy1; selX2[ns] = wx2; selY2[ns] = wy2;
                        selA[ns] = wa; selS[ns] = wsc; selC[ns] = wc;
                    }
                    if (alive) {                        // winner kills itself (IoU=1)
                        float iw = fminf(x2, wx2) - fmaxf(x1, wx1);
                        float ih = fminf(y2, wy2) - fmaxf(y1, wy1);
                        iw = fmaxf(iw, 0.f); ih = fmaxf(ih, 0.f);
                        float inter = iw * ih;
                        if (inter / (area + wa - inter) > 0.5f) alive = false;
                    }
                    ns++;
                }
            }
            if (tid == 0) sh_nsel = ns;
        }
        __syncthreads();
        nsel = sh_nsel;
        hi = lo;
        if (nsel >= MAXB || hi == 0) break;
        if (tid == 0) {                       // next batch's lo via suffix counts
            int sufHi = suf[hi];
            int L = 0, R = hi - 1, res = hi - 1;
            while (L <= R) {
                int m = (L + R) >> 1;
                if (suf[m] - sufHi <= CAP) { res = m; R = m - 1; } else L = m + 1;
            }
            sh_lo = res;
        }
        __syncthreads();
        lo = sh_lo;
        first = false;
        __syncthreads();
    }
    __syncthreads();

    // outputs: boxes[100*4] | scores[100] | classes[100] | num_valid (all fp32)
    for (int k = tid; k < MAXB; k += 256) {
        bool v = k < nsel;
        out[4 * k + 0] = v ? selX1[k] : 0.f;
        out[4 * k + 1] = v ? selY1[k] : 0.f;
        out[4 * k + 2] = v ? selX2[k] : 0.f;
        out[4 * k + 3] = v ? selY2[k] : 0.f;
        out[400 + k] = v ? selS[k] : 0.f;
        out[500 + k] = v ? (float)selC[k] : 0.f;
    }
    if (tid == 0) out[600] = (float)nsel;
}

extern "C" void kernel_launch(void* const* d_in, const int* in_sizes, int n_in,
                              void* d_out, int out_size, void* d_ws, size_t ws_size,
                              hipStream_t stream) {
    const float* g0   = (const float*)d_in[0];
    const float* g1   = (const float*)d_in[1];
    const float* g2   = (const float*)d_in[2];
    const float* anch = (const float*)d_in[3];
    char* ws = (char*)d_ws;
    float* bbox  = (float*)(ws + WS_BBOX);
    float* conf  = (float*)(ws + WS_CONF);
    int*   cls   = (int*)(ws + WS_CLS);
    float* scal  = (float*)(ws + WS_SCAL);
    float* part  = (float*)(ws + WS_PART);
    int*   hist  = (int*)(ws + WS_HIST);
    int*   binc  = (int*)(ws + WS_BINC);
    int*   suf   = (int*)(ws + WS_SUF);
    int*   meta  = (int*)(ws + WS_META);
    unsigned long long* cand = (unsigned long long*)(ws + WS_CAND);
    float* out   = (float*)d_out;

    k_init   <<<144, 256, 0, stream>>>(hist);               // zeros hist+binCtr
    k_decode <<<NTILE, 256, 0, stream>>>(g0, g1, g2, anch, bbox, conf, cls, part);
    k_reduce <<<1, 256, 0, stream>>>(part, scal);
    k_hist   <<<NTOT / 256, 256, 0, stream>>>(conf, scal, hist);
    k_thresh <<<1, 1024, 0, stream>>>(hist, suf, meta);
    k_compact<<<NTOT / 256, 256, 0, stream>>>(conf, scal, suf, meta, binc, cand);
    k_nms    <<<1, 256, 0, stream>>>(bbox, conf, cls, scal, suf, meta, cand, out);
}

// Round 4
// 168.814 us; speedup vs baseline: 2.0259x; 1.2552x over previous
//
#include <hip/hip_runtime.h>
#include <hip/hip_bf16.h>
#include <math.h>

// YOLO decode + hard NMS, exact equivalent of the JAX reference.
// R4: decode writes only conf+partials (bbox/cls recomputed on demand in nms).
// nms = single wave, consumes bin-ordered cand[] in bin-aligned ~256 chunks,
// tiny bitonic sorts, v_readlane accept loop. Exact fallback for lower bins.

#define NCLS  80
#define MAXB  100
#define N0    6912     // 48*48*3
#define N1    27648    // 96*96*3
#define NTOT  145152
#define NTILE 2268     // 64-box tiles
#define NB    4096     // histogram bins (linear in score)
#define CAP   2048     // global candidate capacity (known-safe from R1-R3)
#define CAPL  2048     // nms LDS key capacity (worst single bin / fallback)
#define CHUNK 256      // target chunk size for nms sort+sweep
#define NEGF  -3.402823466e38f
#define POSF   3.402823466e38f

// ws layout (bytes), total ~0.8 MB
#define WS_CONF 0
#define WS_SCAL (NTOT * 4)
#define WS_PART (WS_SCAL + 16)
#define WS_HIST (WS_PART + NTILE * 16)       // 8 shards * NB ints
#define WS_BINC (WS_HIST + 8 * NB * 4)       // NB ints (contiguous after HIST)
#define WS_SUF  (WS_BINC + NB * 4)
#define WS_META (WS_SUF + (NB + 2) * 4)
#define WS_CAND (WS_META + 16)

// Bin index; identical expression everywhere -> identical rounding.
__device__ __forceinline__ int binOf(float s, float Smax) {
    int b = (int)((s / Smax) * (float)NB);
    return b > (NB - 1) ? (NB - 1) : b;
}
__device__ __forceinline__ float smaxOf(const float* scal) {
    float Mx = scal[0], Mn = scal[1], cmx = scal[2], cmn = scal[3];
    return fmaxf(fmaxf(cmx * Mx, cmx * Mn), fmaxf(cmn * Mx, cmn * Mn));
}
__device__ __forceinline__ float rdlane(float v, int l) {
    return __uint_as_float(__builtin_amdgcn_readlane(__float_as_uint(v), l));
}
// Bitwise-identical bbox recompute (same expressions/order as reference decode).
__device__ __forceinline__ void decodeBox(int idx, const float* __restrict__ g0,
        const float* __restrict__ g1, const float* __restrict__ g2,
        const float* __restrict__ anch,
        float& x1, float& y1, float& x2, float& y2) {
    const float* g; int H, ar, j;
    if (idx < N0)           { g = g0; H = 48;  ar = 2; j = idx; }
    else if (idx < N0 + N1) { g = g1; H = 96;  ar = 1; j = idx - N0; }
    else                    { g = g2; H = 192; ar = 0; j = idx - N0 - N1; }
    const float* r = g + (size_t)j * 85;
    float tx = r[0], ty = r[1], tw = r[2], th = r[3];
    int cell = j / 3, a = j - cell * 3;
    int hh = cell / H, ww = cell - hh * H;   // W == H
    float xc = (tx + (float)ww) / (float)H;
    float yc = (ty + (float)hh) / (float)H;
    float bw = expf(tw) * anch[ar * 6 + a * 2];
    float bh = expf(th) * anch[ar * 6 + a * 2 + 1];
    x1 = xc - bw * 0.5f; y1 = yc - bh * 0.5f;
    x2 = xc + bw * 0.5f; y2 = yc + bh * 0.5f;
}

// One 256-thread block per 64-box tile: 4 lanes per box. Writes conf + partials.
__global__ __launch_bounds__(256) void k_decode(
        const float* __restrict__ g0, const float* __restrict__ g1,
        const float* __restrict__ g2, float* __restrict__ conf,
        float* __restrict__ part) {
    __shared__ float sm[5440];                // 64 boxes * 85 ch
    __shared__ float red[16];
    const int tid = threadIdx.x;
    const int tile = blockIdx.x;
    const float* p; int ibase, lt;
    if (tile < 108)      { p = g0; ibase = 0;       lt = tile; }
    else if (tile < 540) { p = g1; ibase = N0;      lt = tile - 108; }
    else                 { p = g2; ibase = N0 + N1; lt = tile - 540; }
    const float4* src = (const float4*)(p + (size_t)lt * 5440);   // 16B-aligned
    for (int w = tid; w < 1360; w += 256) ((float4*)sm)[w] = src[w];
    __syncthreads();

    const int b = tid >> 2, pp = tid & 3;     // 4 lanes per box, same wave
    const float* row = sm + b * 85;
    float best = row[5 + pp * 20];
    #pragma unroll
    for (int k = 1; k < 20; k++) best = fmaxf(best, row[5 + pp * 20 + k]);
    best = fmaxf(best, __shfl_xor(best, 1));  // full-box max on all 4 lanes
    best = fmaxf(best, __shfl_xor(best, 2));
    float cmx = NEGF, cmn = POSF;
    if (pp == 0) {
        float obj = row[4];
        conf[ibase + lt * 64 + b] = obj;
        cmx = obj; cmn = obj;
    }
    // block reduce {max/min box-max, max/min conf} -> plain stores (NO atomics)
    float mpmax = best, mpmin = best;         // all 4 lanes hold box max: min ok
    for (int off = 32; off; off >>= 1) {
        mpmax = fmaxf(mpmax, __shfl_down(mpmax, off));
        mpmin = fminf(mpmin, __shfl_down(mpmin, off));
        cmx   = fmaxf(cmx,   __shfl_down(cmx,   off));
        cmn   = fminf(cmn,   __shfl_down(cmn,   off));
    }
    const int lane = tid & 63, wid = tid >> 6;
    if (lane == 0) {
        red[wid * 4 + 0] = mpmax; red[wid * 4 + 1] = mpmin;
        red[wid * 4 + 2] = cmx;   red[wid * 4 + 3] = cmn;
    }
    __syncthreads();
    if (tid == 0) {
        float a0 = red[0], a1 = red[1], a2 = red[2], a3 = red[3];
        for (int w = 1; w < 4; w++) {
            a0 = fmaxf(a0, red[w * 4 + 0]); a1 = fminf(a1, red[w * 4 + 1]);
            a2 = fmaxf(a2, red[w * 4 + 2]); a3 = fminf(a3, red[w * 4 + 3]);
        }
        part[tile * 4 + 0] = a0; part[tile * 4 + 1] = a1;
        part[tile * 4 + 2] = a2; part[tile * 4 + 3] = a3;
    }
}

__global__ __launch_bounds__(256) void k_reduce(const float* __restrict__ part,
                                                float* __restrict__ scal) {
    __shared__ float red[16];
    const int tid = threadIdx.x;
    float a0 = NEGF, a1 = POSF, a2 = NEGF, a3 = POSF;
    for (int b = tid; b < NTILE; b += 256) {
        a0 = fmaxf(a0, part[b * 4 + 0]); a1 = fminf(a1, part[b * 4 + 1]);
        a2 = fmaxf(a2, part[b * 4 + 2]); a3 = fminf(a3, part[b * 4 + 3]);
    }
    for (int off = 32; off; off >>= 1) {
        a0 = fmaxf(a0, __shfl_down(a0, off)); a1 = fminf(a1, __shfl_down(a1, off));
        a2 = fmaxf(a2, __shfl_down(a2, off)); a3 = fminf(a3, __shfl_down(a3, off));
    }
    const int lane = tid & 63, wid = tid >> 6;
    if (lane == 0) {
        red[wid * 4 + 0] = a0; red[wid * 4 + 1] = a1;
        red[wid * 4 + 2] = a2; red[wid * 4 + 3] = a3;
    }
    __syncthreads();
    if (tid == 0) {
        for (int w = 1; w < 4; w++) {
            a0 = fmaxf(a0, red[w * 4 + 0]); a1 = fminf(a1, red[w * 4 + 1]);
            a2 = fmaxf(a2, red[w * 4 + 2]); a3 = fminf(a3, red[w * 4 + 3]);
        }
        scal[0] = a0; scal[1] = a1; scal[2] = a2; scal[3] = a3;
    }
}

__global__ __launch_bounds__(256) void k_hist(const float* __restrict__ conf,
                                              const float* __restrict__ scal,
                                              int* __restrict__ hist) {
    int i = blockIdx.x * 256 + threadIdx.x;   // grid == NTOT/256 exactly
    float Mx = scal[0], Mn = scal[1];
    float Smax = smaxOf(scal);
    float c = conf[i];
    float s = fmaxf(c * Mx, c * Mn);          // == max_j conf_i * maxprob_j
    if (s > 0.0f && Smax > 0.0f)              // 8-way sharded to spread lines
        atomicAdd(&hist[((blockIdx.x & 7) << 12) + binOf(s, Smax)], 1);
}

__global__ __launch_bounds__(1024) void k_thresh(const int* __restrict__ hist,
                                                 int* __restrict__ suf,
                                                 int* __restrict__ meta) {
    __shared__ int grp[1024];
    const int tid = threadIdx.x;
    int b0 = tid * 4;
    int h[4];
    #pragma unroll
    for (int q = 0; q < 4; q++) {             // sum the 8 shards
        int s = 0;
        #pragma unroll
        for (int sh = 0; sh < 8; sh++) s += hist[sh * NB + b0 + q];
        h[q] = s;
    }
    grp[tid] = h[0] + h[1] + h[2] + h[3];
    __syncthreads();
    for (int d = 1; d < 1024; d <<= 1) {      // Hillis-Steele suffix scan
        int add = (tid + d < 1024) ? grp[tid + d] : 0;
        __syncthreads();
        grp[tid] += add;
        __syncthreads();
    }
    int gnext = (tid + 1 < 1024) ? grp[tid + 1] : 0;
    suf[b0 + 3] = gnext + h[3];
    suf[b0 + 2] = gnext + h[3] + h[2];
    suf[b0 + 1] = gnext + h[3] + h[2] + h[1];
    suf[b0 + 0] = gnext + h[3] + h[2] + h[1] + h[0];
    if (tid == 0) suf[NB] = 0;
    __syncthreads();
    if (tid == 0) {                           // min lo with suffix count <= CAP
        int L = 0, R = NB - 1, res = NB - 1;
        while (L <= R) {
            int m = (L + R) >> 1;
            if (suf[m] <= CAP) { res = m; R = m - 1; } else L = m + 1;
        }
        meta[0] = res;
    }
}

__global__ __launch_bounds__(256) void k_compact(
        const float* __restrict__ conf, const float* __restrict__ scal,
        const int* __restrict__ suf, const int* __restrict__ meta,
        int* __restrict__ binCtr, unsigned long long* __restrict__ cand) {
    int i = blockIdx.x * 256 + threadIdx.x;
    float Mx = scal[0], Mn = scal[1];
    float Smax = smaxOf(scal);
    float c = conf[i];
    float s = fmaxf(c * Mx, c * Mn);
    int lo = meta[0];
    if (s > 0.0f && Smax > 0.0f) {
        int b = binOf(s, Smax);
        if (b >= lo) {
            // exact position: (#cands in higher bins) + rank within bin
            int pos = suf[b + 1] + atomicAdd(&binCtr[b], 1);
            if (pos < CAP)
                // key: score bits | ~idx (ties: smallest idx first in desc sort)
                cand[pos] = ((unsigned long long)__float_as_uint(s) << 32)
                          | (unsigned long long)(~(unsigned)i);
        }
    }
}

// Single wave. Consumes cand[] (bin-descending order) in bin-aligned chunks.
__global__ __launch_bounds__(64) void k_nms(
        const float* __restrict__ g0, const float* __restrict__ g1,
        const float* __restrict__ g2, const float* __restrict__ anch,
        const float* __restrict__ conf, const float* __restrict__ scal,
        const int* __restrict__ suf, const int* __restrict__ meta,
        const unsigned long long* __restrict__ cand, float* __restrict__ out) {
    __shared__ unsigned long long keys[CAPL]; // 16 KB
    __shared__ float selX1[MAXB], selY1[MAXB], selX2[MAXB], selY2[MAXB],
                     selA[MAXB], selS[MAXB];
    __shared__ int selIdx[MAXB];
    __shared__ int sh_cnt;

    const int lane = threadIdx.x;
    const float Mx = scal[0], Mn = scal[1];
    const float Smax = smaxOf(scal);
    const int loGlob = meta[0];
    int nsel = 0;
    int hi = NB;

    while (nsel < MAXB && hi > 0) {
        const bool fast = hi > loGlob;        // cand[] covers bins >= loGlob
        const int sufHi = suf[hi];
        int l;
        {   // min l in [lb, hi) with chunk count <= cap (single over-full bin ok)
            int lb = fast ? loGlob : 0;
            int capHere = fast ? CHUNK : CAPL;
            int L = lb, R = hi - 1, res = hi - 1;
            while (L <= R) {
                int m = (L + R) >> 1;
                if (suf[m] - sufHi <= capHere) { res = m; R = m - 1; } else L = m + 1;
            }
            l = res;                          // l < hi: guaranteed progress
        }
        int cnt;
        if (fast) {
            cnt = suf[l] - sufHi;
            for (int i = lane; i < cnt; i += 64) keys[i] = cand[sufHi + i];
        } else {                              // exact fallback (cold path)
            if (lane == 0) sh_cnt = 0;
            __syncthreads();
            for (int i = lane; i < NTOT; i += 64) {
                float c = conf[i];
                float s = fmaxf(c * Mx, c * Mn);
                if (s > 0.0f) {
                    int b = binOf(s, Smax);
                    if (b >= l && b < hi) {
                        int pos = atomicAdd(&sh_cnt, 1);
                        if (pos < CAPL)
                            keys[pos] = ((unsigned long long)__float_as_uint(s) << 32)
                                      | (unsigned long long)(~(unsigned)i);
                    }
                }
            }
            __syncthreads();
            cnt = sh_cnt; if (cnt > CAPL) cnt = CAPL;
        }
        if (cnt > 0) {
            int n = 2; while (n < cnt) n <<= 1;
            for (int i = cnt + lane; i < n; i += 64) keys[i] = 0ULL;
            __syncthreads();
            // bitonic sort, descending; enumerate pair-slots directly
            for (int k = 2; k <= n; k <<= 1) {
                for (int j = k >> 1; j > 0; j >>= 1) {
                    int half = n >> 1;
                    for (int t = lane; t < half; t += 64) {
                        int i = ((t & ~(j - 1)) << 1) | (t & (j - 1));
                        int ixj = i | j;
                        unsigned long long ka = keys[i], kb = keys[ixj];
                        if ((ka < kb) == ((i & k) == 0)) { keys[i] = kb; keys[ixj] = ka; }
                    }
                    __syncthreads();          // 1-wave block: waitcnt only
                }
            }
            // sweep in 64-wide waves; v_readlane accept loop
            for (int bpos = 0; bpos < cnt && nsel < MAXB; bpos += 64) {
                int t = bpos + lane;
                bool alive = (t < cnt);
                float x1 = 0.f, y1 = 0.f, x2 = 0.f, y2 = 0.f, area = 0.f, sc = 0.f;
                int idx = 0;
                if (alive) {
                    unsigned long long key = keys[t];
                    idx = (int)(~(unsigned)key);
                    sc = __uint_as_float((unsigned)(key >> 32));
                    decodeBox(idx, g0, g1, g2, anch, x1, y1, x2, y2);
                    area = (x2 - x1) * (y2 - y1);
                    for (int s2 = 0; s2 < nsel; s2++) {   // pre-test vs prior sels
                        float iw = fminf(x2, selX2[s2]) - fmaxf(x1, selX1[s2]);
                        float ih = fminf(y2, selY2[s2]) - fmaxf(y1, selY1[s2]);
                        iw = fmaxf(iw, 0.f); ih = fmaxf(ih, 0.f);
                        float inter = iw * ih;
                        if (inter / (area + selA[s2] - inter) > 0.5f) { alive = false; break; }
                    }
                }
                while (nsel < MAXB) {
                    unsigned long long bal = __ballot(alive);
                    if (!bal) break;
                    int w = __ffsll((unsigned long long)bal) - 1;
                    float wx1 = rdlane(x1, w), wy1 = rdlane(y1, w);
                    float wx2 = rdlane(x2, w), wy2 = rdlane(y2, w);
                    float wa  = rdlane(area, w);
                    if (lane == w) {          // winner stores its own entry
                        selX1[nsel] = x1; selY1[nsel] = y1;
                        selX2[nsel] = x2; selY2[nsel] = y2;
                        selA[nsel] = area; selS[nsel] = sc; selIdx[nsel] = idx;
                    }
                    if (alive) {              // winner kills itself (IoU=1)
                        float iw = fminf(x2, wx2) - fmaxf(x1, wx1);
                        float ih = fminf(y2, wy2) - fmaxf(y1, wy1);
                        iw = fmaxf(iw, 0.f); ih = fmaxf(ih, 0.f);
                        float inter = iw * ih;
                        if (inter / (area + wa - inter) > 0.5f) alive = false;
                    }
                    nsel++;
                }
                __syncthreads();
            }
        }
        hi = l;
    }
    __syncthreads();

    // outputs: boxes[100*4] | scores[100] | classes[100] | num_valid (all fp32)
    for (int k = lane; k < MAXB; k += 64) {
        float b0 = 0.f, b1 = 0.f, b2 = 0.f, b3 = 0.f, sv = 0.f, cv = 0.f;
        if (k < nsel) {
            b0 = selX1[k]; b1 = selY1[k]; b2 = selX2[k]; b3 = selY2[k];
            sv = selS[k];
            int idx = selIdx[k];              // class argmax only for selected
            const float* g; int j;
            if (idx < N0)           { g = g0; j = idx; }
            else if (idx < N0 + N1) { g = g1; j = idx - N0; }
            else                    { g = g2; j = idx - N0 - N1; }
            const float* r = g + (size_t)j * 85 + 5;
            float best = r[0]; int c = 0;
            for (int q = 1; q < NCLS; q++) {
                float v = r[q];
                if (v > best) { best = v; c = q; }   // strict > = first max
            }
            cv = (float)c;
        }
        out[4 * k + 0] = b0; out[4 * k + 1] = b1;
        out[4 * k + 2] = b2; out[4 * k + 3] = b3;
        out[400 + k] = sv;
        out[500 + k] = cv;
    }
    if (lane == 0) out[600] = (float)nsel;
}

extern "C" void kernel_launch(void* const* d_in, const int* in_sizes, int n_in,
                              void* d_out, int out_size, void* d_ws, size_t ws_size,
                              hipStream_t stream) {
    const float* g0   = (const float*)d_in[0];
    const float* g1   = (const float*)d_in[1];
    const float* g2   = (const float*)d_in[2];
    const float* anch = (const float*)d_in[3];
    char* ws = (char*)d_ws;
    float* conf  = (float*)(ws + WS_CONF);
    float* scal  = (float*)(ws + WS_SCAL);
    float* part  = (float*)(ws + WS_PART);
    int*   hist  = (int*)(ws + WS_HIST);
    int*   binc  = (int*)(ws + WS_BINC);
    int*   suf   = (int*)(ws + WS_SUF);
    int*   meta  = (int*)(ws + WS_META);
    unsigned long long* cand = (unsigned long long*)(ws + WS_CAND);
    float* out   = (float*)d_out;

    hipMemsetAsync(ws + WS_HIST, 0, 9 * NB * 4, stream);    // hist shards + binCtr
    k_decode <<<NTILE, 256, 0, stream>>>(g0, g1, g2, conf, part);
    k_reduce <<<1, 256, 0, stream>>>(part, scal);
    k_hist   <<<NTOT / 256, 256, 0, stream>>>(conf, scal, hist);
    k_thresh <<<1, 1024, 0, stream>>>(hist, suf, meta);
    k_compact<<<NTOT / 256, 256, 0, stream>>>(conf, scal, suf, meta, binc, cand);
    k_nms    <<<1, 64, 0, stream>>>(g0, g1, g2, anch, conf, scal, suf, meta, cand, out);
}